// Round 13
// baseline (605.042 us; speedup 1.0000x reference)
//
#include <hip/hip_runtime.h>
#define S_LEN 2048
#define HDIM 4096
#define NHEAD 32
#define QKD 192
#define RQ_ 1536
#define CKV_W 576
#define KVW 8192
#define QFW 6144
#define SC2F 0.1041216313667742f

typedef float f32x4 __attribute__((ext_vector_type(4)));
typedef __bf16 bf16x8 __attribute__((ext_vector_type(8)));

__device__ __forceinline__ unsigned short f2bf(float f) {
  unsigned int u = __float_as_uint(f);
  u += 0x7fffu + ((u >> 16) & 1u);
  return (unsigned short)(u >> 16);
}
__device__ __forceinline__ float b2f(unsigned short u) {
  return __uint_as_float((unsigned int)u << 16);
}
__device__ __forceinline__ float ex2(float x) { return exp2f(x); }

__device__ __forceinline__ void stage16(const void* g, void* lds_base, int lane) {
  __builtin_amdgcn_global_load_lds(
      (const __attribute__((address_space(1))) unsigned int*)g,
      (__attribute__((address_space(3))) unsigned int*)lds_base, 16, 0, 0);
}

__global__ __launch_bounds__(256) void cvt_kernel(
    const float* __restrict__ in, unsigned short* __restrict__ out, int n8) {
  int i = blockIdx.x * 256 + threadIdx.x;
  if (i >= n8) return;
  const float4* p = reinterpret_cast<const float4*>(in) + (size_t)i * 2;
  float4 a = p[0], b = p[1];
  unsigned long long lo = (unsigned long long)f2bf(a.x) | ((unsigned long long)f2bf(a.y) << 16)
      | ((unsigned long long)f2bf(a.z) << 32) | ((unsigned long long)f2bf(a.w) << 48);
  unsigned long long hi = (unsigned long long)f2bf(b.x) | ((unsigned long long)f2bf(b.y) << 16)
      | ((unsigned long long)f2bf(b.z) << 32) | ((unsigned long long)f2bf(b.w) << 48);
  unsigned long long* q = reinterpret_cast<unsigned long long*>(out) + (size_t)i * 2;
  q[0] = lo; q[1] = hi;
}

// BK=64 2-phase dbuf 128x128 GEMM: 64 KB LDS (2 blocks/CU), half the
// barriers of BK=32, 32 MFMA/wave per barrier. K must be %64.
template<bool BF16OUT, bool SPLITK>
__global__ __launch_bounds__(256) void gemm_bf(
    const unsigned short* __restrict__ A, int lda,
    const unsigned short* __restrict__ B, int ldb,
    void* __restrict__ Cv, int ldc, int N, int K) {
  __shared__ unsigned short As[2][8][128][8];
  __shared__ unsigned short Bs[2][8][128][8];
  const int tid = threadIdx.x, lane = tid & 63, w = tid >> 6;
  const int gx = (int)gridDim.x;
  const int nwg = gx * (int)gridDim.y;
  int lin = (int)blockIdx.y * gx + (int)blockIdx.x;
  if ((nwg & 7) == 0) lin = (lin & 7) * (nwg >> 3) + (lin >> 3);
  const int bm = (lin / gx) * 128, bn = (lin % gx) * 128;
  const int koff = SPLITK ? (int)blockIdx.z * K : 0;
  const int wr = (w >> 1) * 64, wc = (w & 1) * 64;
  const int lg = lane >> 4, lm = lane & 15;
  f32x4 acc[4][4] = {};
  const int arow = bm + lane;
  int brow = bn + lane; if (brow >= N) brow = N - 1;

  auto STAGE = [&](int buf, int k0) {
#pragma unroll
    for (int kk = 0; kk < 2; ++kk) {
      int kg = kk * 4 + w;
#pragma unroll
      for (int i = 0; i < 2; ++i) {
        stage16(A + (size_t)(arow + i * 64) * lda + koff + k0 + kg * 8,
                &As[buf][kg][i * 64][0], lane);
        int br2 = brow + i * 64; if (br2 >= N) br2 = N - 1;
        stage16(B + (size_t)br2 * ldb + koff + k0 + kg * 8,
                &Bs[buf][kg][i * 64][0], lane);
      }
    }
  };
  STAGE(0, 0);
  __syncthreads();
  int cur = 0;
  for (int k0 = 0; k0 < K; k0 += 64) {
    if (k0 + 64 < K) STAGE(cur ^ 1, k0 + 64);
#pragma unroll
    for (int kk = 0; kk < 2; ++kk) {
      bf16x8 af[4], bf[4];
#pragma unroll
      for (int i = 0; i < 4; ++i)
        af[i] = *reinterpret_cast<const bf16x8*>(&As[cur][kk * 4 + lg][wr + i * 16 + lm][0]);
#pragma unroll
      for (int j = 0; j < 4; ++j)
        bf[j] = *reinterpret_cast<const bf16x8*>(&Bs[cur][kk * 4 + lg][wc + j * 16 + lm][0]);
      __builtin_amdgcn_s_setprio(1);
#pragma unroll
      for (int i = 0; i < 4; ++i)
#pragma unroll
        for (int j = 0; j < 4; ++j)
          acc[i][j] = __builtin_amdgcn_mfma_f32_16x16x32_bf16(af[i], bf[j], acc[i][j], 0, 0, 0);
      __builtin_amdgcn_s_setprio(0);
    }
    __syncthreads();
    cur ^= 1;
  }
  size_t zoff = SPLITK ? (size_t)blockIdx.z * S_LEN * N : 0;
#pragma unroll
  for (int i = 0; i < 4; ++i)
#pragma unroll
    for (int j = 0; j < 4; ++j)
#pragma unroll
      for (int r = 0; r < 4; ++r) {
        int row = bm + wr + i * 16 + lg * 4 + r;
        int col = bn + wc + j * 16 + lm;
        if (col < N) {
          if constexpr (BF16OUT)
            ((unsigned short*)Cv)[(size_t)row * ldc + col] = f2bf(acc[i][j][r]);
          else
            ((float*)Cv)[zoff + (size_t)row * ldc + col] = acc[i][j][r];
        }
      }
}

__global__ __launch_bounds__(256) void rms_sum_q(
    const float* __restrict__ P, const float* __restrict__ w,
    unsigned short* __restrict__ y) {
  __shared__ float red[4];
  const int row = blockIdx.x, tid = threadIdx.x;
  const float* base = P + (size_t)row * RQ_;
  float x[6]; float ss = 0.f;
#pragma unroll
  for (int ii = 0; ii < 6; ++ii) {
    int j = tid + ii * 256;
    float v = 0.f;
#pragma unroll
    for (int z = 0; z < 4; ++z) v += base[(size_t)z * S_LEN * RQ_ + j];
    x[ii] = v; ss += v * v;
  }
#pragma unroll
  for (int off = 1; off < 64; off <<= 1) ss += __shfl_xor(ss, off, 64);
  if ((tid & 63) == 0) red[tid >> 6] = ss;
  __syncthreads();
  float scale = rsqrtf((red[0] + red[1] + red[2] + red[3]) / (float)RQ_ + 1e-6f);
  unsigned short* q = y + (size_t)row * RQ_;
#pragma unroll
  for (int ii = 0; ii < 6; ++ii) {
    int j = tid + ii * 256;
    q[j] = f2bf(x[ii] * scale * w[j]);
  }
}

__global__ __launch_bounds__(256) void rms_sum_kv(
    const float* __restrict__ P, const float* __restrict__ w,
    unsigned short* __restrict__ y, float* __restrict__ rotf) {
  __shared__ float red[4];
  const int row = blockIdx.x, tid = threadIdx.x;
  const float* base = P + (size_t)row * CKV_W;
  float x0 = 0.f, x1 = 0.f, x2 = 0.f;
#pragma unroll
  for (int z = 0; z < 8; ++z) {
    const float* b = base + (size_t)z * S_LEN * CKV_W;
    x0 += b[tid]; x1 += b[tid + 256];
    if (tid < 64) x2 += b[tid + 512];
  }
  float ss = x0 * x0 + x1 * x1;
#pragma unroll
  for (int off = 1; off < 64; off <<= 1) ss += __shfl_xor(ss, off, 64);
  if ((tid & 63) == 0) red[tid >> 6] = ss;
  __syncthreads();
  float scale = rsqrtf((red[0] + red[1] + red[2] + red[3]) / 512.0f + 1e-6f);
  unsigned short* q = y + (size_t)row * 512;
  q[tid] = f2bf(x0 * scale * w[tid]);
  q[tid + 256] = f2bf(x1 * scale * w[tid + 256]);
  if (tid < 64) rotf[(size_t)row * 64 + tid] = x2;
}

__global__ __launch_bounds__(256) void build_q_kernel(
    const unsigned short* __restrict__ qf, const float* __restrict__ freqs,
    unsigned short* __restrict__ Q) {
  int idx = blockIdx.x * 256 + threadIdx.x;
  if (idx >= NHEAD * S_LEN * 96) return;
  int j = idx % 96, s = (idx / 96) % S_LEN, h = idx / (96 * S_LEN);
  const unsigned short* src = qf + (size_t)s * QFW + h * QKD;
  unsigned int pk;
  if (j < 64) {
    pk = *reinterpret_cast<const unsigned int*>(&src[2 * j]);
  } else {
    int r = j - 64;
    float xr = b2f(src[128 + 2 * r]), xi = b2f(src[128 + 2 * r + 1]);
    float f = freqs[(size_t)s * 32 + r];
    float c = cosf(f), sn = sinf(f);
    pk = (unsigned int)f2bf(xr * c - xi * sn) | ((unsigned int)f2bf(xr * sn + xi * c) << 16);
  }
  *reinterpret_cast<unsigned int*>(Q + ((size_t)(h * S_LEN + s) * QKD + 2 * j)) = pk;
}

__global__ __launch_bounds__(256) void build_k_kernel(
    const unsigned short* __restrict__ kv, const float* __restrict__ rotf,
    const float* __restrict__ freqs, unsigned short* __restrict__ K) {
  int idx = blockIdx.x * 256 + threadIdx.x;
  if (idx >= NHEAD * S_LEN * 96) return;
  int j = idx % 96, s = (idx / 96) % S_LEN, h = idx / (96 * S_LEN);
  unsigned int pk;
  if (j < 64) {
    pk = *reinterpret_cast<const unsigned int*>(&kv[(size_t)s * KVW + h * 256 + 2 * j]);
  } else {
    int r = j - 64;
    float xr = rotf[(size_t)s * 64 + 2 * r];
    float xi = rotf[(size_t)s * 64 + 2 * r + 1];
    float f = freqs[(size_t)s * 32 + r];
    float c = cosf(f), sn = sinf(f);
    pk = (unsigned int)f2bf(xr * c - xi * sn) | ((unsigned int)f2bf(xr * sn + xi * c) << 16);
  }
  *reinterpret_cast<unsigned int*>(K + ((size_t)(h * S_LEN + s) * QKD + 2 * j)) = pk;
}

__global__ __launch_bounds__(256) void build_vt_kernel(
    const unsigned short* __restrict__ kv, unsigned short* __restrict__ Vt) {
  __shared__ unsigned short T[128][33];
  const int tid = threadIdx.x;
  const int h = blockIdx.y, s0 = blockIdx.x * 32;
#pragma unroll
  for (int p = 0; p < 16; ++p) {
    int i = p * 256 + tid;
    int d = i & 127, sr = i >> 7;
    T[d][sr] = kv[(size_t)(s0 + sr) * KVW + h * 256 + 128 + d];
  }
  __syncthreads();
#pragma unroll
  for (int p = 0; p < 8; ++p) {
    int i = p * 256 + tid;
    int d = i >> 4, sp = (i & 15) * 2;
    unsigned int pk = (unsigned int)T[d][sp] | ((unsigned int)T[d][sp + 1] << 16);
    *reinterpret_cast<unsigned int*>(Vt + (size_t)(h * 128 + d) * S_LEN + s0 + sp) = pk;
  }
}

__global__ __launch_bounds__(256, 2) void attn_kernel(
    const unsigned short* __restrict__ Q,
    const unsigned short* __restrict__ K,
    const unsigned short* __restrict__ Vt,
    unsigned short* __restrict__ O) {
  __shared__ unsigned short Ks[2][32 * 192];
  __shared__ unsigned short Vs[2][128 * 32];
  __shared__ unsigned short Ps[4][32 * 32];
  const int tid = threadIdx.x, lane = tid & 63, w = tid >> 6;
  const int wg = (int)blockIdx.x;
  const int lin = (wg & 7) * 64 + (wg >> 3);
  const int h = lin >> 4;
  const int qt = 15 - (lin & 15);
  const int qr0 = qt * 128 + w * 32;
  const int lg = lane >> 4, lm = lane & 15, lm7 = lane & 7;
  const unsigned short* Qh = Q + (size_t)h * S_LEN * QKD;
  const unsigned short* Kh = K + (size_t)h * S_LEN * QKD;
  const unsigned short* Vh = Vt + (size_t)h * 128 * S_LEN;

  bf16x8 qf[2][6];
#pragma unroll
  for (int a = 0; a < 2; ++a)
#pragma unroll
    for (int f = 0; f < 6; ++f)
      qf[a][f] = *reinterpret_cast<const bf16x8*>(
          Qh + (size_t)(qr0 + a * 16 + lm) * QKD + f * 32 + lg * 8);

  f32x4 o[2][8] = {};
  float l[2][4] = {};

  auto STAGE = [&](int b, int kp) {
#pragma unroll
    for (int i = 0; i < 3; ++i) {
      int fb = (w * 3 + i) * 64 + lane;
      int row = fb / 24;
      int blk = fb - row * 24;
      int gb = (blk & ~7) | ((blk ^ row) & 7);
      stage16(Kh + (size_t)(kp + row) * QKD + gb * 8, &Ks[b][(w * 3 + i) * 512], lane);
    }
#pragma unroll
    for (int i = 0; i < 2; ++i) {
      int fb = (w * 2 + i) * 64 + lane;
      int row = fb >> 2;
      int blk = fb & 3;
      stage16(Vh + (size_t)row * S_LEN + kp + blk * 8, &Vs[b][(w * 2 + i) * 512], lane);
    }
  };

  const int ntiles = (qt + 1) * 4;
  STAGE(0, 0);
  __syncthreads();
  int buf = 0;
  for (int ti = 0; ti < ntiles; ++ti) {
    const int kp = ti * 32;
    if (ti + 1 < ntiles) STAGE(buf ^ 1, kp + 32);
    if (kp <= qr0 + 31) {
      f32x4 sc[2][2] = {};
      __builtin_amdgcn_s_setprio(1);
#pragma unroll
      for (int f = 0; f < 6; ++f)
#pragma unroll
        for (int c = 0; c < 2; ++c) {
          int blk = f * 4 + lg;
          int sb = (blk & ~7) | ((blk ^ lm7) & 7);
          bf16x8 kf = *reinterpret_cast<const bf16x8*>(&Ks[buf][(c * 16 + lm) * 192 + sb * 8]);
          sc[0][c] = __builtin_amdgcn_mfma_f32_16x16x32_bf16(qf[0][f], kf, sc[0][c], 0, 0, 0);
          sc[1][c] = __builtin_amdgcn_mfma_f32_16x16x32_bf16(qf[1][f], kf, sc[1][c], 0, 0, 0);
        }
      __builtin_amdgcn_s_setprio(0);
#pragma unroll
      for (int a = 0; a < 2; ++a) {
        const int rb = qr0 + a * 16 + lg * 4;
#pragma unroll
        for (int r = 0; r < 4; ++r) {
          const int row = rb + r;
          float v0 = fmaf(sc[a][0][r], SC2F, -32.f); if (kp + lm > row) v0 = -1e9f;
          float v1 = fmaf(sc[a][1][r], SC2F, -32.f); if (kp + 16 + lm > row) v1 = -1e9f;
          float p0 = ex2(v0), p1 = ex2(v1);
          l[a][r] += p0 + p1;
          int pr = a * 16 + lg * 4 + r;
          int s3 = (pr >> 2) & 3;
          int b0 = lm >> 3;
          unsigned short* pp = &Ps[w][pr * 32];
          pp[((b0 ^ s3) << 3) + lm7] = f2bf(p0);
          pp[(((2 + b0) ^ s3) << 3) + lm7] = f2bf(p1);
        }
      }
      bf16x8 pa[2];
#pragma unroll
      for (int a = 0; a < 2; ++a)
        pa[a] = *reinterpret_cast<const bf16x8*>(
            &Ps[w][(a * 16 + lm) * 32 + ((lg ^ ((lm >> 2) & 3)) << 3)]);
      __builtin_amdgcn_s_setprio(1);
#pragma unroll
      for (int d = 0; d < 8; ++d) {
        bf16x8 vf = *reinterpret_cast<const bf16x8*>(&Vs[buf][(d * 16 + lm) * 32 + lg * 8]);
        o[0][d] = __builtin_amdgcn_mfma_f32_16x16x32_bf16(pa[0], vf, o[0][d], 0, 0, 0);
        o[1][d] = __builtin_amdgcn_mfma_f32_16x16x32_bf16(pa[1], vf, o[1][d], 0, 0, 0);
      }
      __builtin_amdgcn_s_setprio(0);
    }
    __syncthreads();
    buf ^= 1;
  }
#pragma unroll
  for (int a = 0; a < 2; ++a)
#pragma unroll
    for (int r = 0; r < 4; ++r) {
      float t = l[a][r];
#pragma unroll
      for (int off = 1; off < 16; off <<= 1) t += __shfl_xor(t, off, 16);
      float inv = 1.0f / t;
      int row = qr0 + a * 16 + lg * 4 + r;
#pragma unroll
      for (int d = 0; d < 8; ++d)
        O[(size_t)row * 4096 + h * 128 + d * 16 + lm] = f2bf(o[a][d][r] * inv);
    }
}

extern "C" void kernel_launch(void* const* d_in, const int* in_sizes, int n_in,
                              void* d_out, int out_size, void* d_ws, size_t ws_size,
                              hipStream_t stream) {
  const float* hs = (const float*)d_in[0];
  const float* freqs = (const float*)d_in[1];
  const float* q_a_w = (const float*)d_in[2];
  const float* q_a_ln = (const float*)d_in[3];
  const float* q_b_w = (const float*)d_in[4];
  const float* kv_a_w = (const float*)d_in[5];
  const float* kv_a_ln = (const float*)d_in[6];
  const float* kv_b_w = (const float*)d_in[7];
  const float* o_w = (const float*)d_in[8];
  float* out = (float*)d_out;

  char* ws = (char*)d_ws;
  unsigned short* wslot = (unsigned short*)(ws + 0);
  unsigned short* hs_bf = (unsigned short*)(ws + 33554432);
  unsigned short* attnb = (unsigned short*)(ws + 33554432);
  float* qa_part = (float*)(ws + 50331648);
  unsigned short* kv_bf = (unsigned short*)(ws + 50331648);
  float* ckv_part = (float*)(ws + 100663296);
  unsigned short* Qb = (unsigned short*)(ws + 100663296);
  unsigned short* qa_bf = (unsigned short*)(ws + 138412032);
  unsigned short* ckv_bf = (unsigned short*)(ws + 144703488);
  float* rotf = (float*)(ws + 146800640);
  unsigned short* qfullb = (unsigned short*)(ws + 147324928);
  unsigned short* Kb = (unsigned short*)(ws + 147324928);
  unsigned short* Vt = (unsigned short*)(ws + 172490752);

  dim3 blk(256);
  auto cvt = [&](const float* src, unsigned short* dst, size_t n) {
    int n8 = (int)(n / 8);
    cvt_kernel<<<(n8 + 255) / 256, blk, 0, stream>>>(src, dst, n8);
  };

  cvt(hs, hs_bf, (size_t)S_LEN * HDIM);
  cvt(q_a_w, wslot, (size_t)RQ_ * HDIM);
  gemm_bf<false, true><<<dim3(RQ_ / 128, S_LEN / 128, 4), blk, 0, stream>>>(
      hs_bf, HDIM, wslot, HDIM, qa_part, RQ_, RQ_, HDIM / 4);
  cvt(kv_a_w, wslot, (size_t)CKV_W * HDIM);
  gemm_bf<false, true><<<dim3((CKV_W + 127) / 128, S_LEN / 128, 8), blk, 0, stream>>>(
      hs_bf, HDIM, wslot, HDIM, ckv_part, CKV_W, CKV_W, HDIM / 8);
  rms_sum_q<<<S_LEN, blk, 0, stream>>>(qa_part, q_a_ln, qa_bf);
  rms_sum_kv<<<S_LEN, blk, 0, stream>>>(ckv_part, kv_a_ln, ckv_bf, rotf);
  cvt(q_b_w, wslot, (size_t)QFW * RQ_);
  gemm_bf<true, false><<<dim3(QFW / 128, S_LEN / 128), blk, 0, stream>>>(
      qa_bf, RQ_, wslot, RQ_, qfullb, QFW, QFW, RQ_);
  cvt(kv_b_w, wslot, (size_t)KVW * 512);
  gemm_bf<true, false><<<dim3(KVW / 128, S_LEN / 128), blk, 0, stream>>>(
      ckv_bf, 512, wslot, 512, kv_bf, KVW, KVW, 512);
  build_q_kernel<<<(NHEAD * S_LEN * 96 + 255) / 256, blk, 0, stream>>>(qfullb, freqs, Qb);
  build_k_kernel<<<(NHEAD * S_LEN * 96 + 255) / 256, blk, 0, stream>>>(kv_bf, rotf, freqs, Kb);
  build_vt_kernel<<<dim3(S_LEN / 32, NHEAD), blk, 0, stream>>>(kv_bf, Vt);
  attn_kernel<<<dim3(512), blk, 0, stream>>>(Qb, Kb, Vt, attnb);
  cvt(o_w, wslot, (size_t)HDIM * HDIM);
  gemm_bf<false, false><<<dim3(HDIM / 128, S_LEN / 128), blk, 0, stream>>>(
      attnb, HDIM, wslot, HDIM, out, HDIM, HDIM, HDIM);
}

// Round 14
// 562.188 us; speedup vs baseline: 1.0762x; 1.0762x over previous
//
#include <hip/hip_runtime.h>
#define S_LEN 2048
#define HDIM 4096
#define NHEAD 32
#define QKD 192
#define RQ_ 1536
#define CKV_W 576
#define KVW 8192
#define QFW 6144
#define SC2F 0.1041216313667742f

typedef float f32x4 __attribute__((ext_vector_type(4)));
typedef __bf16 bf16x8 __attribute__((ext_vector_type(8)));

__device__ __forceinline__ unsigned short f2bf(float f) {
  unsigned int u = __float_as_uint(f);
  u += 0x7fffu + ((u >> 16) & 1u);
  return (unsigned short)(u >> 16);
}
__device__ __forceinline__ float b2f(unsigned short u) {
  return __uint_as_float((unsigned int)u << 16);
}
__device__ __forceinline__ float ex2(float x) { return exp2f(x); }

__device__ __forceinline__ void stage16(const void* g, void* lds_base, int lane) {
  __builtin_amdgcn_global_load_lds(
      (const __attribute__((address_space(1))) unsigned int*)g,
      (__attribute__((address_space(3))) unsigned int*)lds_base, 16, 0, 0);
}

__global__ __launch_bounds__(256) void cvt_kernel(
    const float* __restrict__ in, unsigned short* __restrict__ out, int n8) {
  int i = blockIdx.x * 256 + threadIdx.x;
  if (i >= n8) return;
  const float4* p = reinterpret_cast<const float4*>(in) + (size_t)i * 2;
  float4 a = p[0], b = p[1];
  unsigned long long lo = (unsigned long long)f2bf(a.x) | ((unsigned long long)f2bf(a.y) << 16)
      | ((unsigned long long)f2bf(a.z) << 32) | ((unsigned long long)f2bf(a.w) << 48);
  unsigned long long hi = (unsigned long long)f2bf(b.x) | ((unsigned long long)f2bf(b.y) << 16)
      | ((unsigned long long)f2bf(b.z) << 32) | ((unsigned long long)f2bf(b.w) << 48);
  unsigned long long* q = reinterpret_cast<unsigned long long*>(out) + (size_t)i * 2;
  q[0] = lo; q[1] = hi;
}

// R12-proven: BK=32 2-phase dbuf 128x128 GEMM, 32 KB LDS, 2 blocks/CU.
template<bool BF16OUT, bool SPLITK>
__global__ __launch_bounds__(256) void gemm_bf(
    const unsigned short* __restrict__ A, int lda,
    const unsigned short* __restrict__ B, int ldb,
    void* __restrict__ Cv, int ldc, int N, int K) {
  __shared__ unsigned short As[2][4][128][8];
  __shared__ unsigned short Bs[2][4][128][8];
  const int tid = threadIdx.x, lane = tid & 63, w = tid >> 6;
  const int gx = (int)gridDim.x;
  const int nwg = gx * (int)gridDim.y;
  int lin = (int)blockIdx.y * gx + (int)blockIdx.x;
  if ((nwg & 7) == 0) lin = (lin & 7) * (nwg >> 3) + (lin >> 3);
  const int bm = (lin / gx) * 128, bn = (lin % gx) * 128;
  const int koff = SPLITK ? (int)blockIdx.z * K : 0;
  const int wr = (w >> 1) * 64, wc = (w & 1) * 64;
  const int lg = lane >> 4, lm = lane & 15;
  f32x4 acc[4][4] = {};
  const int arow = bm + lane;
  int brow = bn + lane; if (brow >= N) brow = N - 1;

  auto STAGE = [&](int buf, int k0) {
#pragma unroll
    for (int i = 0; i < 2; ++i) {
      stage16(A + (size_t)(arow + i * 64) * lda + koff + k0 + w * 8, &As[buf][w][i * 64][0], lane);
      int br2 = brow + i * 64; if (br2 >= N) br2 = N - 1;
      stage16(B + (size_t)br2 * ldb + koff + k0 + w * 8, &Bs[buf][w][i * 64][0], lane);
    }
  };
  STAGE(0, 0);
  __syncthreads();
  int cur = 0;
  for (int k0 = 0; k0 < K; k0 += 32) {
    if (k0 + 32 < K) STAGE(cur ^ 1, k0 + 32);
    bf16x8 af[4], bf[4];
#pragma unroll
    for (int i = 0; i < 4; ++i)
      af[i] = *reinterpret_cast<const bf16x8*>(&As[cur][lg][wr + i * 16 + lm][0]);
#pragma unroll
    for (int j = 0; j < 4; ++j)
      bf[j] = *reinterpret_cast<const bf16x8*>(&Bs[cur][lg][wc + j * 16 + lm][0]);
    __builtin_amdgcn_s_setprio(1);
#pragma unroll
    for (int i = 0; i < 4; ++i)
#pragma unroll
      for (int j = 0; j < 4; ++j)
        acc[i][j] = __builtin_amdgcn_mfma_f32_16x16x32_bf16(af[i], bf[j], acc[i][j], 0, 0, 0);
    __builtin_amdgcn_s_setprio(0);
    __syncthreads();
    cur ^= 1;
  }
  size_t zoff = SPLITK ? (size_t)blockIdx.z * S_LEN * N : 0;
#pragma unroll
  for (int i = 0; i < 4; ++i)
#pragma unroll
    for (int j = 0; j < 4; ++j)
#pragma unroll
      for (int r = 0; r < 4; ++r) {
        int row = bm + wr + i * 16 + lg * 4 + r;
        int col = bn + wc + j * 16 + lm;
        if (col < N) {
          if constexpr (BF16OUT)
            ((unsigned short*)Cv)[(size_t)row * ldc + col] = f2bf(acc[i][j][r]);
          else
            ((float*)Cv)[zoff + (size_t)row * ldc + col] = acc[i][j][r];
        }
      }
}

__global__ __launch_bounds__(256) void rms_sum_q(
    const float* __restrict__ P, const float* __restrict__ w,
    unsigned short* __restrict__ y) {
  __shared__ float red[4];
  const int row = blockIdx.x, tid = threadIdx.x;
  const float* base = P + (size_t)row * RQ_;
  float x[6]; float ss = 0.f;
#pragma unroll
  for (int ii = 0; ii < 6; ++ii) {
    int j = tid + ii * 256;
    float v = 0.f;
#pragma unroll
    for (int z = 0; z < 4; ++z) v += base[(size_t)z * S_LEN * RQ_ + j];
    x[ii] = v; ss += v * v;
  }
#pragma unroll
  for (int off = 1; off < 64; off <<= 1) ss += __shfl_xor(ss, off, 64);
  if ((tid & 63) == 0) red[tid >> 6] = ss;
  __syncthreads();
  float scale = rsqrtf((red[0] + red[1] + red[2] + red[3]) / (float)RQ_ + 1e-6f);
  unsigned short* q = y + (size_t)row * RQ_;
#pragma unroll
  for (int ii = 0; ii < 6; ++ii) {
    int j = tid + ii * 256;
    q[j] = f2bf(x[ii] * scale * w[j]);
  }
}

__global__ __launch_bounds__(256) void rms_sum_kv(
    const float* __restrict__ P, const float* __restrict__ w,
    unsigned short* __restrict__ y, float* __restrict__ rotf) {
  __shared__ float red[4];
  const int row = blockIdx.x, tid = threadIdx.x;
  const float* base = P + (size_t)row * CKV_W;
  float x0 = 0.f, x1 = 0.f, x2 = 0.f;
#pragma unroll
  for (int z = 0; z < 8; ++z) {
    const float* b = base + (size_t)z * S_LEN * CKV_W;
    x0 += b[tid]; x1 += b[tid + 256];
    if (tid < 64) x2 += b[tid + 512];
  }
  float ss = x0 * x0 + x1 * x1;
#pragma unroll
  for (int off = 1; off < 64; off <<= 1) ss += __shfl_xor(ss, off, 64);
  if ((tid & 63) == 0) red[tid >> 6] = ss;
  __syncthreads();
  float scale = rsqrtf((red[0] + red[1] + red[2] + red[3]) / 512.0f + 1e-6f);
  unsigned short* q = y + (size_t)row * 512;
  q[tid] = f2bf(x0 * scale * w[tid]);
  q[tid + 256] = f2bf(x1 * scale * w[tid + 256]);
  if (tid < 64) rotf[(size_t)row * 64 + tid] = x2;
}

__global__ __launch_bounds__(256) void build_q_kernel(
    const unsigned short* __restrict__ qf, const float* __restrict__ freqs,
    unsigned short* __restrict__ Q) {
  int idx = blockIdx.x * 256 + threadIdx.x;
  if (idx >= NHEAD * S_LEN * 96) return;
  int j = idx % 96, s = (idx / 96) % S_LEN, h = idx / (96 * S_LEN);
  const unsigned short* src = qf + (size_t)s * QFW + h * QKD;
  unsigned int pk;
  if (j < 64) {
    pk = *reinterpret_cast<const unsigned int*>(&src[2 * j]);
  } else {
    int r = j - 64;
    float xr = b2f(src[128 + 2 * r]), xi = b2f(src[128 + 2 * r + 1]);
    float f = freqs[(size_t)s * 32 + r];
    float c = cosf(f), sn = sinf(f);
    pk = (unsigned int)f2bf(xr * c - xi * sn) | ((unsigned int)f2bf(xr * sn + xi * c) << 16);
  }
  *reinterpret_cast<unsigned int*>(Q + ((size_t)(h * S_LEN + s) * QKD + 2 * j)) = pk;
}

__global__ __launch_bounds__(256) void build_k_kernel(
    const unsigned short* __restrict__ kv, const float* __restrict__ rotf,
    const float* __restrict__ freqs, unsigned short* __restrict__ K) {
  int idx = blockIdx.x * 256 + threadIdx.x;
  if (idx >= NHEAD * S_LEN * 96) return;
  int j = idx % 96, s = (idx / 96) % S_LEN, h = idx / (96 * S_LEN);
  unsigned int pk;
  if (j < 64) {
    pk = *reinterpret_cast<const unsigned int*>(&kv[(size_t)s * KVW + h * 256 + 2 * j]);
  } else {
    int r = j - 64;
    float xr = rotf[(size_t)s * 64 + 2 * r];
    float xi = rotf[(size_t)s * 64 + 2 * r + 1];
    float f = freqs[(size_t)s * 32 + r];
    float c = cosf(f), sn = sinf(f);
    pk = (unsigned int)f2bf(xr * c - xi * sn) | ((unsigned int)f2bf(xr * sn + xi * c) << 16);
  }
  *reinterpret_cast<unsigned int*>(K + ((size_t)(h * S_LEN + s) * QKD + 2 * j)) = pk;
}

__global__ __launch_bounds__(256) void build_vt_kernel(
    const unsigned short* __restrict__ kv, unsigned short* __restrict__ Vt) {
  __shared__ unsigned short T[128][33];
  const int tid = threadIdx.x;
  const int h = blockIdx.y, s0 = blockIdx.x * 32;
#pragma unroll
  for (int p = 0; p < 16; ++p) {
    int i = p * 256 + tid;
    int d = i & 127, sr = i >> 7;
    T[d][sr] = kv[(size_t)(s0 + sr) * KVW + h * 256 + 128 + d];
  }
  __syncthreads();
#pragma unroll
  for (int p = 0; p < 8; ++p) {
    int i = p * 256 + tid;
    int d = i >> 4, sp = (i & 15) * 2;
    unsigned int pk = (unsigned int)T[d][sp] | ((unsigned int)T[d][sp + 1] << 16);
    *reinterpret_cast<unsigned int*>(Vt + (size_t)(h * 128 + d) * S_LEN + s0 + sp) = pk;
  }
}

// QBLK=64 (4 waves x 16 q-rows), KVB=32, dbuf staging, 44 KB LDS -> 3 blk/CU.
// Grid 1024 XCD-chunked (4 heads/XCD -> K/V L2-resident).
__global__ __launch_bounds__(256, 3) void attn_kernel(
    const unsigned short* __restrict__ Q,
    const unsigned short* __restrict__ K,
    const unsigned short* __restrict__ Vt,
    unsigned short* __restrict__ O) {
  __shared__ unsigned short Ks[2][32 * 192];
  __shared__ unsigned short Vs[2][128 * 32];
  __shared__ unsigned short Ps[4][16 * 32];
  const int tid = threadIdx.x, lane = tid & 63, w = tid >> 6;
  const int wg = (int)blockIdx.x;
  const int lin = (wg & 7) * 128 + (wg >> 3);   // 1024 % 8 == 0, bijective
  const int h = lin >> 5;
  const int qt = 31 - (lin & 31);               // heavy-first
  const int qr0 = qt * 64 + w * 16;
  const int lg = lane >> 4, lm = lane & 15, lm7 = lane & 7;
  const unsigned short* Qh = Q + (size_t)h * S_LEN * QKD;
  const unsigned short* Kh = K + (size_t)h * S_LEN * QKD;
  const unsigned short* Vh = Vt + (size_t)h * 128 * S_LEN;

  bf16x8 qf[6];
#pragma unroll
  for (int f = 0; f < 6; ++f)
    qf[f] = *reinterpret_cast<const bf16x8*>(
        Qh + (size_t)(qr0 + lm) * QKD + f * 32 + lg * 8);

  f32x4 o[8] = {};
  float l[4] = {};

  auto STAGE = [&](int b, int kp) {
#pragma unroll
    for (int i = 0; i < 3; ++i) {
      int fb = (w * 3 + i) * 64 + lane;
      int row = fb / 24;
      int blk = fb - row * 24;
      int gb = (blk & ~7) | ((blk ^ row) & 7);
      stage16(Kh + (size_t)(kp + row) * QKD + gb * 8, &Ks[b][(w * 3 + i) * 512], lane);
    }
#pragma unroll
    for (int i = 0; i < 2; ++i) {
      int fb = (w * 2 + i) * 64 + lane;
      int row = fb >> 2;
      int blk = fb & 3;
      stage16(Vh + (size_t)row * S_LEN + kp + blk * 8, &Vs[b][(w * 2 + i) * 512], lane);
    }
  };

  const int ntiles = (qt + 1) * 2;
  STAGE(0, 0);
  __syncthreads();
  int buf = 0;
  for (int ti = 0; ti < ntiles; ++ti) {
    const int kp = ti * 32;
    if (ti + 1 < ntiles) STAGE(buf ^ 1, kp + 32);
    if (kp <= qr0 + 15) {
      f32x4 sc[2] = {};
      __builtin_amdgcn_s_setprio(1);
#pragma unroll
      for (int f = 0; f < 6; ++f)
#pragma unroll
        for (int c = 0; c < 2; ++c) {
          int blk = f * 4 + lg;
          int sb = (blk & ~7) | ((blk ^ lm7) & 7);
          bf16x8 kf = *reinterpret_cast<const bf16x8*>(&Ks[buf][(c * 16 + lm) * 192 + sb * 8]);
          sc[c] = __builtin_amdgcn_mfma_f32_16x16x32_bf16(qf[f], kf, sc[c], 0, 0, 0);
        }
      __builtin_amdgcn_s_setprio(0);
      const int rb = qr0 + lg * 4;
#pragma unroll
      for (int r = 0; r < 4; ++r) {
        const int row = rb + r;
        float v0 = fmaf(sc[0][r], SC2F, -32.f); if (kp + lm > row) v0 = -1e9f;
        float v1 = fmaf(sc[1][r], SC2F, -32.f); if (kp + 16 + lm > row) v1 = -1e9f;
        float p0 = ex2(v0), p1 = ex2(v1);
        l[r] += p0 + p1;
        int pr = lg * 4 + r;
        int s3 = pr & 3;
        int b0 = lm >> 3;
        unsigned short* pp = &Ps[w][pr * 32];
        pp[((b0 ^ s3) << 3) + lm7] = f2bf(p0);
        pp[(((2 + b0) ^ s3) << 3) + lm7] = f2bf(p1);
      }
      bf16x8 pa = *reinterpret_cast<const bf16x8*>(
          &Ps[w][lm * 32 + ((lg ^ (lm & 3)) << 3)]);
      __builtin_amdgcn_s_setprio(1);
#pragma unroll
      for (int d = 0; d < 8; ++d) {
        bf16x8 vf = *reinterpret_cast<const bf16x8*>(&Vs[buf][(d * 16 + lm) * 32 + lg * 8]);
        o[d] = __builtin_amdgcn_mfma_f32_16x16x32_bf16(pa, vf, o[d], 0, 0, 0);
      }
      __builtin_amdgcn_s_setprio(0);
    }
    __syncthreads();
    buf ^= 1;
  }
#pragma unroll
  for (int r = 0; r < 4; ++r) {
    float t = l[r];
#pragma unroll
    for (int off = 1; off < 16; off <<= 1) t += __shfl_xor(t, off, 16);
    float inv = 1.0f / t;
    int row = qr0 + lg * 4 + r;
#pragma unroll
    for (int d = 0; d < 8; ++d)
      O[(size_t)row * 4096 + h * 128 + d * 16 + lm] = f2bf(o[d][r] * inv);
  }
}

extern "C" void kernel_launch(void* const* d_in, const int* in_sizes, int n_in,
                              void* d_out, int out_size, void* d_ws, size_t ws_size,
                              hipStream_t stream) {
  const float* hs = (const float*)d_in[0];
  const float* freqs = (const float*)d_in[1];
  const float* q_a_w = (const float*)d_in[2];
  const float* q_a_ln = (const float*)d_in[3];
  const float* q_b_w = (const float*)d_in[4];
  const float* kv_a_w = (const float*)d_in[5];
  const float* kv_a_ln = (const float*)d_in[6];
  const float* kv_b_w = (const float*)d_in[7];
  const float* o_w = (const float*)d_in[8];
  float* out = (float*)d_out;

  char* ws = (char*)d_ws;
  unsigned short* wslot = (unsigned short*)(ws + 0);
  unsigned short* hs_bf = (unsigned short*)(ws + 33554432);
  unsigned short* attnb = (unsigned short*)(ws + 33554432);
  float* qa_part = (float*)(ws + 50331648);
  unsigned short* kv_bf = (unsigned short*)(ws + 50331648);
  float* ckv_part = (float*)(ws + 100663296);
  unsigned short* Qb = (unsigned short*)(ws + 100663296);
  unsigned short* qa_bf = (unsigned short*)(ws + 138412032);
  unsigned short* ckv_bf = (unsigned short*)(ws + 144703488);
  float* rotf = (float*)(ws + 146800640);
  unsigned short* qfullb = (unsigned short*)(ws + 147324928);
  unsigned short* Kb = (unsigned short*)(ws + 147324928);
  unsigned short* Vt = (unsigned short*)(ws + 172490752);

  dim3 blk(256);
  auto cvt = [&](const float* src, unsigned short* dst, size_t n) {
    int n8 = (int)(n / 8);
    cvt_kernel<<<(n8 + 255) / 256, blk, 0, stream>>>(src, dst, n8);
  };

  cvt(hs, hs_bf, (size_t)S_LEN * HDIM);
  cvt(q_a_w, wslot, (size_t)RQ_ * HDIM);
  gemm_bf<false, true><<<dim3(RQ_ / 128, S_LEN / 128, 4), blk, 0, stream>>>(
      hs_bf, HDIM, wslot, HDIM, qa_part, RQ_, RQ_, HDIM / 4);
  cvt(kv_a_w, wslot, (size_t)CKV_W * HDIM);
  gemm_bf<false, true><<<dim3((CKV_W + 127) / 128, S_LEN / 128, 8), blk, 0, stream>>>(
      hs_bf, HDIM, wslot, HDIM, ckv_part, CKV_W, CKV_W, HDIM / 8);
  rms_sum_q<<<S_LEN, blk, 0, stream>>>(qa_part, q_a_ln, qa_bf);
  rms_sum_kv<<<S_LEN, blk, 0, stream>>>(ckv_part, kv_a_ln, ckv_bf, rotf);
  cvt(q_b_w, wslot, (size_t)QFW * RQ_);
  gemm_bf<true, false><<<dim3(QFW / 128, S_LEN / 128), blk, 0, stream>>>(
      qa_bf, RQ_, wslot, RQ_, qfullb, QFW, QFW, RQ_);
  cvt(kv_b_w, wslot, (size_t)KVW * 512);
  gemm_bf<true, false><<<dim3(KVW / 128, S_LEN / 128), blk, 0, stream>>>(
      ckv_bf, 512, wslot, 512, kv_bf, KVW, KVW, 512);
  build_q_kernel<<<(NHEAD * S_LEN * 96 + 255) / 256, blk, 0, stream>>>(qfullb, freqs, Qb);
  build_k_kernel<<<(NHEAD * S_LEN * 96 + 255) / 256, blk, 0, stream>>>(kv_bf, rotf, freqs, Kb);
  build_vt_kernel<<<dim3(S_LEN / 32, NHEAD), blk, 0, stream>>>(kv_bf, Vt);
  attn_kernel<<<dim3(1024), blk, 0, stream>>>(Qb, Kb, Vt, attnb);
  cvt(o_w, wslot, (size_t)HDIM * HDIM);
  gemm_bf<false, false><<<dim3(HDIM / 128, S_LEN / 128), blk, 0, stream>>>(
      attnb, HDIM, wslot, HDIM, out, HDIM, HDIM, HDIM);
}

// Round 15
// 551.398 us; speedup vs baseline: 1.0973x; 1.0196x over previous
//
#include <hip/hip_runtime.h>
#define S_LEN 2048
#define HDIM 4096
#define NHEAD 32
#define QKD 192
#define RQ_ 1536
#define CKV_W 576
#define KVW 8192
#define QFW 6144
#define SC2F 0.1041216313667742f

typedef float f32x4 __attribute__((ext_vector_type(4)));
typedef __bf16 bf16x8 __attribute__((ext_vector_type(8)));

__device__ __forceinline__ unsigned short f2bf(float f) {
  unsigned int u = __float_as_uint(f);
  u += 0x7fffu + ((u >> 16) & 1u);
  return (unsigned short)(u >> 16);
}
__device__ __forceinline__ float b2f(unsigned short u) {
  return __uint_as_float((unsigned int)u << 16);
}
__device__ __forceinline__ float ex2(float x) { return exp2f(x); }

__device__ __forceinline__ void stage16(const void* g, void* lds_base, int lane) {
  __builtin_amdgcn_global_load_lds(
      (const __attribute__((address_space(1))) unsigned int*)g,
      (__attribute__((address_space(3))) unsigned int*)lds_base, 16, 0, 0);
}

__global__ __launch_bounds__(256) void cvt_kernel(
    const float* __restrict__ in, unsigned short* __restrict__ out, int n8) {
  int i = blockIdx.x * 256 + threadIdx.x;
  if (i >= n8) return;
  const float4* p = reinterpret_cast<const float4*>(in) + (size_t)i * 2;
  float4 a = p[0], b = p[1];
  unsigned long long lo = (unsigned long long)f2bf(a.x) | ((unsigned long long)f2bf(a.y) << 16)
      | ((unsigned long long)f2bf(a.z) << 32) | ((unsigned long long)f2bf(a.w) << 48);
  unsigned long long hi = (unsigned long long)f2bf(b.x) | ((unsigned long long)f2bf(b.y) << 16)
      | ((unsigned long long)f2bf(b.z) << 32) | ((unsigned long long)f2bf(b.w) << 48);
  unsigned long long* q = reinterpret_cast<unsigned long long*>(out) + (size_t)i * 2;
  q[0] = lo; q[1] = hi;
}

// BK=32 2-phase dbuf 128x128 GEMM. Decode is M-fast: consecutive (XCD-chunked)
// blocks share a 1 MB B-panel (L2-resident) and stream A panels.
template<bool BF16OUT, bool SPLITK>
__global__ __launch_bounds__(256) void gemm_bf(
    const unsigned short* __restrict__ A, int lda,
    const unsigned short* __restrict__ B, int ldb,
    void* __restrict__ Cv, int ldc, int N, int K) {
  __shared__ unsigned short As[2][4][128][8];
  __shared__ unsigned short Bs[2][4][128][8];
  const int tid = threadIdx.x, lane = tid & 63, w = tid >> 6;
  const int gx = (int)gridDim.x, gy = (int)gridDim.y;
  const int nwg = gx * gy;
  int lin = (int)blockIdx.y * gx + (int)blockIdx.x;
  if ((nwg & 7) == 0) lin = (lin & 7) * (nwg >> 3) + (lin >> 3);
  const int bm = (lin % gy) * 128, bn = (lin / gy) * 128;
  const int koff = SPLITK ? (int)blockIdx.z * K : 0;
  const int wr = (w >> 1) * 64, wc = (w & 1) * 64;
  const int lg = lane >> 4, lm = lane & 15;
  f32x4 acc[4][4] = {};
  const int arow = bm + lane;
  int brow = bn + lane; if (brow >= N) brow = N - 1;

  auto STAGE = [&](int buf, int k0) {
#pragma unroll
    for (int i = 0; i < 2; ++i) {
      stage16(A + (size_t)(arow + i * 64) * lda + koff + k0 + w * 8, &As[buf][w][i * 64][0], lane);
      int br2 = brow + i * 64; if (br2 >= N) br2 = N - 1;
      stage16(B + (size_t)br2 * ldb + koff + k0 + w * 8, &Bs[buf][w][i * 64][0], lane);
    }
  };
  STAGE(0, 0);
  __syncthreads();
  int cur = 0;
  for (int k0 = 0; k0 < K; k0 += 32) {
    if (k0 + 32 < K) STAGE(cur ^ 1, k0 + 32);
    bf16x8 af[4], bf[4];
#pragma unroll
    for (int i = 0; i < 4; ++i)
      af[i] = *reinterpret_cast<const bf16x8*>(&As[cur][lg][wr + i * 16 + lm][0]);
#pragma unroll
    for (int j = 0; j < 4; ++j)
      bf[j] = *reinterpret_cast<const bf16x8*>(&Bs[cur][lg][wc + j * 16 + lm][0]);
    __builtin_amdgcn_s_setprio(1);
#pragma unroll
    for (int i = 0; i < 4; ++i)
#pragma unroll
      for (int j = 0; j < 4; ++j)
        acc[i][j] = __builtin_amdgcn_mfma_f32_16x16x32_bf16(af[i], bf[j], acc[i][j], 0, 0, 0);
    __builtin_amdgcn_s_setprio(0);
    __syncthreads();
    cur ^= 1;
  }
  size_t zoff = SPLITK ? (size_t)blockIdx.z * S_LEN * N : 0;
#pragma unroll
  for (int i = 0; i < 4; ++i)
#pragma unroll
    for (int j = 0; j < 4; ++j)
#pragma unroll
      for (int r = 0; r < 4; ++r) {
        int row = bm + wr + i * 16 + lg * 4 + r;
        int col = bn + wc + j * 16 + lm;
        if (col < N) {
          if constexpr (BF16OUT)
            ((unsigned short*)Cv)[(size_t)row * ldc + col] = f2bf(acc[i][j][r]);
          else
            ((float*)Cv)[zoff + (size_t)row * ldc + col] = acc[i][j][r];
        }
      }
}

__global__ __launch_bounds__(256) void rms_sum_q(
    const float* __restrict__ P, const float* __restrict__ w,
    unsigned short* __restrict__ y) {
  __shared__ float red[4];
  const int row = blockIdx.x, tid = threadIdx.x;
  const float* base = P + (size_t)row * RQ_;
  float x[6]; float ss = 0.f;
#pragma unroll
  for (int ii = 0; ii < 6; ++ii) {
    int j = tid + ii * 256;
    float v = 0.f;
#pragma unroll
    for (int z = 0; z < 4; ++z) v += base[(size_t)z * S_LEN * RQ_ + j];
    x[ii] = v; ss += v * v;
  }
#pragma unroll
  for (int off = 1; off < 64; off <<= 1) ss += __shfl_xor(ss, off, 64);
  if ((tid & 63) == 0) red[tid >> 6] = ss;
  __syncthreads();
  float scale = rsqrtf((red[0] + red[1] + red[2] + red[3]) / (float)RQ_ + 1e-6f);
  unsigned short* q = y + (size_t)row * RQ_;
#pragma unroll
  for (int ii = 0; ii < 6; ++ii) {
    int j = tid + ii * 256;
    q[j] = f2bf(x[ii] * scale * w[j]);
  }
}

__global__ __launch_bounds__(256) void rms_sum_kv(
    const float* __restrict__ P, const float* __restrict__ w,
    unsigned short* __restrict__ y, float* __restrict__ rotf) {
  __shared__ float red[4];
  const int row = blockIdx.x, tid = threadIdx.x;
  const float* base = P + (size_t)row * CKV_W;
  float x0 = 0.f, x1 = 0.f, x2 = 0.f;
#pragma unroll
  for (int z = 0; z < 8; ++z) {
    const float* b = base + (size_t)z * S_LEN * CKV_W;
    x0 += b[tid]; x1 += b[tid + 256];
    if (tid < 64) x2 += b[tid + 512];
  }
  float ss = x0 * x0 + x1 * x1;
#pragma unroll
  for (int off = 1; off < 64; off <<= 1) ss += __shfl_xor(ss, off, 64);
  if ((tid & 63) == 0) red[tid >> 6] = ss;
  __syncthreads();
  float scale = rsqrtf((red[0] + red[1] + red[2] + red[3]) / 512.0f + 1e-6f);
  unsigned short* q = y + (size_t)row * 512;
  q[tid] = f2bf(x0 * scale * w[tid]);
  q[tid + 256] = f2bf(x1 * scale * w[tid + 256]);
  if (tid < 64) rotf[(size_t)row * 64 + tid] = x2;
}

__global__ __launch_bounds__(256) void build_q_kernel(
    const unsigned short* __restrict__ qf, const float* __restrict__ freqs,
    unsigned short* __restrict__ Q) {
  int idx = blockIdx.x * 256 + threadIdx.x;
  if (idx >= NHEAD * S_LEN * 96) return;
  int j = idx % 96, s = (idx / 96) % S_LEN, h = idx / (96 * S_LEN);
  const unsigned short* src = qf + (size_t)s * QFW + h * QKD;
  unsigned int pk;
  if (j < 64) {
    pk = *reinterpret_cast<const unsigned int*>(&src[2 * j]);
  } else {
    int r = j - 64;
    float xr = b2f(src[128 + 2 * r]), xi = b2f(src[128 + 2 * r + 1]);
    float f = freqs[(size_t)s * 32 + r];
    float c = cosf(f), sn = sinf(f);
    pk = (unsigned int)f2bf(xr * c - xi * sn) | ((unsigned int)f2bf(xr * sn + xi * c) << 16);
  }
  *reinterpret_cast<unsigned int*>(Q + ((size_t)(h * S_LEN + s) * QKD + 2 * j)) = pk;
}

__global__ __launch_bounds__(256) void build_k_kernel(
    const unsigned short* __restrict__ kv, const float* __restrict__ rotf,
    const float* __restrict__ freqs, unsigned short* __restrict__ K) {
  int idx = blockIdx.x * 256 + threadIdx.x;
  if (idx >= NHEAD * S_LEN * 96) return;
  int j = idx % 96, s = (idx / 96) % S_LEN, h = idx / (96 * S_LEN);
  unsigned int pk;
  if (j < 64) {
    pk = *reinterpret_cast<const unsigned int*>(&kv[(size_t)s * KVW + h * 256 + 2 * j]);
  } else {
    int r = j - 64;
    float xr = rotf[(size_t)s * 64 + 2 * r];
    float xi = rotf[(size_t)s * 64 + 2 * r + 1];
    float f = freqs[(size_t)s * 32 + r];
    float c = cosf(f), sn = sinf(f);
    pk = (unsigned int)f2bf(xr * c - xi * sn) | ((unsigned int)f2bf(xr * sn + xi * c) << 16);
  }
  *reinterpret_cast<unsigned int*>(K + ((size_t)(h * S_LEN + s) * QKD + 2 * j)) = pk;
}

__global__ __launch_bounds__(256) void build_vt_kernel(
    const unsigned short* __restrict__ kv, unsigned short* __restrict__ Vt) {
  __shared__ unsigned short T[128][33];
  const int tid = threadIdx.x;
  const int h = blockIdx.y, s0 = blockIdx.x * 32;
#pragma unroll
  for (int p = 0; p < 16; ++p) {
    int i = p * 256 + tid;
    int d = i & 127, sr = i >> 7;
    T[d][sr] = kv[(size_t)(s0 + sr) * KVW + h * 256 + 128 + d];
  }
  __syncthreads();
#pragma unroll
  for (int p = 0; p < 8; ++p) {
    int i = p * 256 + tid;
    int d = i >> 4, sp = (i & 15) * 2;
    unsigned int pk = (unsigned int)T[d][sp] | ((unsigned int)T[d][sp + 1] << 16);
    *reinterpret_cast<unsigned int*>(Vt + (size_t)(h * 128 + d) * S_LEN + s0 + sp) = pk;
  }
}

// QBLK=64 (4 waves x 16 q-rows), KVB=32, dbuf staging, 44 KB LDS, 3 blk/CU.
__global__ __launch_bounds__(256, 3) void attn_kernel(
    const unsigned short* __restrict__ Q,
    const unsigned short* __restrict__ K,
    const unsigned short* __restrict__ Vt,
    unsigned short* __restrict__ O) {
  __shared__ unsigned short Ks[2][32 * 192];
  __shared__ unsigned short Vs[2][128 * 32];
  __shared__ unsigned short Ps[4][16 * 32];
  const int tid = threadIdx.x, lane = tid & 63, w = tid >> 6;
  const int wg = (int)blockIdx.x;
  const int lin = (wg & 7) * 128 + (wg >> 3);
  const int h = lin >> 5;
  const int qt = 31 - (lin & 31);
  const int qr0 = qt * 64 + w * 16;
  const int lg = lane >> 4, lm = lane & 15, lm7 = lane & 7;
  const unsigned short* Qh = Q + (size_t)h * S_LEN * QKD;
  const unsigned short* Kh = K + (size_t)h * S_LEN * QKD;
  const unsigned short* Vh = Vt + (size_t)h * 128 * S_LEN;

  bf16x8 qf[6];
#pragma unroll
  for (int f = 0; f < 6; ++f)
    qf[f] = *reinterpret_cast<const bf16x8*>(
        Qh + (size_t)(qr0 + lm) * QKD + f * 32 + lg * 8);

  f32x4 o[8] = {};
  float l[4] = {};

  auto STAGE = [&](int b, int kp) {
#pragma unroll
    for (int i = 0; i < 3; ++i) {
      int fb = (w * 3 + i) * 64 + lane;
      int row = fb / 24;
      int blk = fb - row * 24;
      int gb = (blk & ~7) | ((blk ^ row) & 7);
      stage16(Kh + (size_t)(kp + row) * QKD + gb * 8, &Ks[b][(w * 3 + i) * 512], lane);
    }
#pragma unroll
    for (int i = 0; i < 2; ++i) {
      int fb = (w * 2 + i) * 64 + lane;
      int row = fb >> 2;
      int blk = fb & 3;
      stage16(Vh + (size_t)row * S_LEN + kp + blk * 8, &Vs[b][(w * 2 + i) * 512], lane);
    }
  };

  const int ntiles = (qt + 1) * 2;
  STAGE(0, 0);
  __syncthreads();
  int buf = 0;
  for (int ti = 0; ti < ntiles; ++ti) {
    const int kp = ti * 32;
    if (ti + 1 < ntiles) STAGE(buf ^ 1, kp + 32);
    if (kp <= qr0 + 15) {
      f32x4 sc[2] = {};
      __builtin_amdgcn_s_setprio(1);
#pragma unroll
      for (int f = 0; f < 6; ++f)
#pragma unroll
        for (int c = 0; c < 2; ++c) {
          int blk = f * 4 + lg;
          int sb = (blk & ~7) | ((blk ^ lm7) & 7);
          bf16x8 kf = *reinterpret_cast<const bf16x8*>(&Ks[buf][(c * 16 + lm) * 192 + sb * 8]);
          sc[c] = __builtin_amdgcn_mfma_f32_16x16x32_bf16(qf[f], kf, sc[c], 0, 0, 0);
        }
      __builtin_amdgcn_s_setprio(0);
      const int rb = qr0 + lg * 4;
#pragma unroll
      for (int r = 0; r < 4; ++r) {
        const int row = rb + r;
        float v0 = fmaf(sc[0][r], SC2F, -32.f); if (kp + lm > row) v0 = -1e9f;
        float v1 = fmaf(sc[1][r], SC2F, -32.f); if (kp + 16 + lm > row) v1 = -1e9f;
        float p0 = ex2(v0), p1 = ex2(v1);
        l[r] += p0 + p1;
        int pr = lg * 4 + r;
        int s3 = pr & 3;
        int b0 = lm >> 3;
        unsigned short* pp = &Ps[w][pr * 32];
        pp[((b0 ^ s3) << 3) + lm7] = f2bf(p0);
        pp[(((2 + b0) ^ s3) << 3) + lm7] = f2bf(p1);
      }
      bf16x8 pa = *reinterpret_cast<const bf16x8*>(
          &Ps[w][lm * 32 + ((lg ^ (lm & 3)) << 3)]);
      __builtin_amdgcn_s_setprio(1);
#pragma unroll
      for (int d = 0; d < 8; ++d) {
        bf16x8 vf = *reinterpret_cast<const bf16x8*>(&Vs[buf][(d * 16 + lm) * 32 + lg * 8]);
        o[d] = __builtin_amdgcn_mfma_f32_16x16x32_bf16(pa, vf, o[d], 0, 0, 0);
      }
      __builtin_amdgcn_s_setprio(0);
    }
    __syncthreads();
    buf ^= 1;
  }
#pragma unroll
  for (int r = 0; r < 4; ++r) {
    float t = l[r];
#pragma unroll
    for (int off = 1; off < 16; off <<= 1) t += __shfl_xor(t, off, 16);
    float inv = 1.0f / t;
    int row = qr0 + lg * 4 + r;
#pragma unroll
    for (int d = 0; d < 8; ++d)
      O[(size_t)row * 4096 + h * 128 + d * 16 + lm] = f2bf(o[d][r] * inv);
  }
}

extern "C" void kernel_launch(void* const* d_in, const int* in_sizes, int n_in,
                              void* d_out, int out_size, void* d_ws, size_t ws_size,
                              hipStream_t stream) {
  const float* hs = (const float*)d_in[0];
  const float* freqs = (const float*)d_in[1];
  const float* q_a_w = (const float*)d_in[2];
  const float* q_a_ln = (const float*)d_in[3];
  const float* q_b_w = (const float*)d_in[4];
  const float* kv_a_w = (const float*)d_in[5];
  const float* kv_a_ln = (const float*)d_in[6];
  const float* kv_b_w = (const float*)d_in[7];
  const float* o_w = (const float*)d_in[8];
  float* out = (float*)d_out;

  char* ws = (char*)d_ws;
  unsigned short* wslot = (unsigned short*)(ws + 0);
  unsigned short* hs_bf = (unsigned short*)(ws + 33554432);
  unsigned short* attnb = (unsigned short*)(ws + 33554432);
  float* qa_part = (float*)(ws + 50331648);
  unsigned short* kv_bf = (unsigned short*)(ws + 50331648);
  float* ckv_part = (float*)(ws + 100663296);
  unsigned short* Qb = (unsigned short*)(ws + 100663296);
  unsigned short* qa_bf = (unsigned short*)(ws + 138412032);
  unsigned short* ckv_bf = (unsigned short*)(ws + 144703488);
  float* rotf = (float*)(ws + 146800640);
  unsigned short* qfullb = (unsigned short*)(ws + 147324928);
  unsigned short* Kb = (unsigned short*)(ws + 147324928);
  unsigned short* Vt = (unsigned short*)(ws + 172490752);

  dim3 blk(256);
  auto cvt = [&](const float* src, unsigned short* dst, size_t n) {
    int n8 = (int)(n / 8);
    cvt_kernel<<<(n8 + 255) / 256, blk, 0, stream>>>(src, dst, n8);
  };

  cvt(hs, hs_bf, (size_t)S_LEN * HDIM);
  cvt(q_a_w, wslot, (size_t)RQ_ * HDIM);
  gemm_bf<false, true><<<dim3(RQ_ / 128, S_LEN / 128, 4), blk, 0, stream>>>(
      hs_bf, HDIM, wslot, HDIM, qa_part, RQ_, RQ_, HDIM / 4);
  cvt(kv_a_w, wslot, (size_t)CKV_W * HDIM);
  gemm_bf<false, true><<<dim3((CKV_W + 127) / 128, S_LEN / 128, 8), blk, 0, stream>>>(
      hs_bf, HDIM, wslot, HDIM, ckv_part, CKV_W, CKV_W, HDIM / 8);
  rms_sum_q<<<S_LEN, blk, 0, stream>>>(qa_part, q_a_ln, qa_bf);
  rms_sum_kv<<<S_LEN, blk, 0, stream>>>(ckv_part, kv_a_ln, ckv_bf, rotf);
  cvt(q_b_w, wslot, (size_t)QFW * RQ_);
  gemm_bf<true, false><<<dim3(QFW / 128, S_LEN / 128), blk, 0, stream>>>(
      qa_bf, RQ_, wslot, RQ_, qfullb, QFW, QFW, RQ_);
  cvt(kv_b_w, wslot, (size_t)KVW * 512);
  gemm_bf<true, false><<<dim3(KVW / 128, S_LEN / 128), blk, 0, stream>>>(
      ckv_bf, 512, wslot, 512, kv_bf, KVW, KVW, 512);
  build_q_kernel<<<(NHEAD * S_LEN * 96 + 255) / 256, blk, 0, stream>>>(qfullb, freqs, Qb);
  build_k_kernel<<<(NHEAD * S_LEN * 96 + 255) / 256, blk, 0, stream>>>(kv_bf, rotf, freqs, Kb);
  build_vt_kernel<<<dim3(S_LEN / 32, NHEAD), blk, 0, stream>>>(kv_bf, Vt);
  attn_kernel<<<dim3(1024), blk, 0, stream>>>(Qb, Kb, Vt, attnb);
  cvt(o_w, wslot, (size_t)HDIM * HDIM);
  gemm_bf<false, false><<<dim3(HDIM / 128, S_LEN / 128), blk, 0, stream>>>(
      attnb, HDIM, wslot, HDIM, out, HDIM, HDIM, HDIM);
}